// Round 4
// baseline (227.889 us; speedup 1.0000x reference)
//
#include <hip/hip_runtime.h>
#include <math.h>

// minGRU bidirectional scan — 3-kernel chunked decomposition for parallelism.
// x: [8, 512, 8192] fp32. out: [8, 256, 8192] fp32.
//   a_t = sigmoid(-gate_t); b_t = sigmoid(gate_t)*g(h_t); H_t = a_t*H_{t-1} + b_t
//   g(h) = h>=0 ? h+1 : exp(h)
//
// 2048 sequences (8 batch x 128 ch x 2 dir), each split into 16 chunks of 512.
// k1: per-chunk transform aggregate (A,B)   — one wave per chunk (32768 waves)
// k2: per-sequence fold of 16 aggregates into 16 entering STATES (scalar, h0=0)
// k3: per-chunk full scan seeded with entering state; write output.

#define SEQ_L 8192
#define PER_LANE 8
#define CHUNK 512                   // 64 lanes * 8
#define NCHUNK (SEQ_L / CHUNK)      // 16
#define NSEQ 2048
#define NCHUNK_TOTAL (NSEQ * NCHUNK) // 32768

// decode chunk id -> pointers and physical base for this lane
__device__ __forceinline__ void chunk_addr(const float* __restrict__ x,
                                           int gchunk, int lane,
                                           const float*& hrow, const float*& grow,
                                           int& seq, int& k, int& dir, int& p) {
    seq = gchunk >> 4;          // 0..2047
    k   = gchunk & 15;          // chunk index in scan order
    dir = seq >> 10;            // 0 fwd, 1 bwd
    const int s = seq & 1023;
    const int b = s >> 7;
    const int c = s & 127;
    hrow = x + (size_t)((b * 512) + (dir * 256) + c) * SEQ_L;
    grow = hrow + (size_t)128 * SEQ_L;
    const int base = k * CHUNK + lane * PER_LANE;   // scan-order index
    p = dir ? (SEQ_L - base - PER_LANE) : base;     // physical index of 8-run
}

// load 8 h,g values in SCAN order (reverse the float4s for backward)
__device__ __forceinline__ void load8(const float* hrow, const float* grow,
                                      int p, int dir,
                                      float* hv, float* gv) {
    const float4 h0 = *(const float4*)(hrow + p);
    const float4 h1 = *(const float4*)(hrow + p + 4);
    const float4 g0 = *(const float4*)(grow + p);
    const float4 g1 = *(const float4*)(grow + p + 4);
    if (dir == 0) {
        hv[0]=h0.x; hv[1]=h0.y; hv[2]=h0.z; hv[3]=h0.w;
        hv[4]=h1.x; hv[5]=h1.y; hv[6]=h1.z; hv[7]=h1.w;
        gv[0]=g0.x; gv[1]=g0.y; gv[2]=g0.z; gv[3]=g0.w;
        gv[4]=g1.x; gv[5]=g1.y; gv[6]=g1.z; gv[7]=g1.w;
    } else {
        hv[0]=h1.w; hv[1]=h1.z; hv[2]=h1.y; hv[3]=h1.x;
        hv[4]=h0.w; hv[5]=h0.z; hv[6]=h0.y; hv[7]=h0.x;
        gv[0]=g1.w; gv[1]=g1.z; gv[2]=g1.y; gv[3]=g1.x;
        gv[4]=g0.w; gv[5]=g0.z; gv[6]=g0.y; gv[7]=g0.x;
    }
}

__device__ __forceinline__ void coeffs(float gt, float hh, float& a, float& bb) {
    const float e  = __expf(-fabsf(gt));
    const float r  = 1.0f / (1.0f + e);
    const float sn = e * r;                   // sigmoid(-|gt|)
    const float z  = (gt >= 0.0f) ? r  : sn;  // sigmoid(gt)
    a  = (gt >= 0.0f) ? sn : r;               // sigmoid(-gt)
    const float gf = (hh >= 0.0f) ? (hh + 1.0f) : __expf(hh);
    bb = z * gf;
}

// ---------------- k1: chunk aggregates ----------------
__global__ __launch_bounds__(256) void k_agg(const float* __restrict__ x,
                                             float2* __restrict__ agg) {
    const int lane = threadIdx.x & 63;
    const int gchunk = blockIdx.x * 4 + (threadIdx.x >> 6);
    const float *hrow, *grow; int seq, k, dir, p;
    chunk_addr(x, gchunk, lane, hrow, grow, seq, k, dir, p);

    float hv[PER_LANE], gv[PER_LANE];
    load8(hrow, grow, p, dir, hv, gv);

    float pa = 1.0f, pb = 0.0f;   // this lane's 8-element transform
#pragma unroll
    for (int j = 0; j < PER_LANE; ++j) {
        float a, bb; coeffs(gv[j], hv[j], a, bb);
        pb = a * pb + bb;
        pa = a * pa;
    }
    // tree compose: lane i accumulates [i .. i+2d-1]; lane 0 ends with full chunk
#pragma unroll
    for (int d = 1; d < 64; d <<= 1) {
        const float oa = __shfl_down(pa, d);   // later segment
        const float ob = __shfl_down(pb, d);
        pa = pa * oa;            // A = A_earlier * A_later
        pb = oa * pb + ob;       // B = A_later*B_earlier + B_later
    }
    if (lane == 0) agg[gchunk] = make_float2(pa, pb);
}

// ---------------- k2: entering states per chunk ----------------
__global__ __launch_bounds__(256) void k_states(const float2* __restrict__ agg,
                                                float* __restrict__ st) {
    const int seq = blockIdx.x * 256 + threadIdx.x;   // 0..2047
    float s = 0.0f;                                   // initial hidden state
#pragma unroll
    for (int k = 0; k < NCHUNK; ++k) {
        st[seq * NCHUNK + k] = s;
        const float2 ab = agg[seq * NCHUNK + k];
        s = ab.x * s + ab.y;
    }
}

// ---------------- k3: apply ----------------
__global__ __launch_bounds__(256) void k_apply(const float* __restrict__ x,
                                               const float* __restrict__ st,
                                               float* __restrict__ out) {
    const int lane = threadIdx.x & 63;
    const int gchunk = blockIdx.x * 4 + (threadIdx.x >> 6);
    const float *hrow, *grow; int seq, k, dir, p;
    chunk_addr(x, gchunk, lane, hrow, grow, seq, k, dir, p);

    const int s_  = seq & 1023;
    const int b   = s_ >> 7;
    const int c   = s_ & 127;
    float* __restrict__ orow = out + (size_t)((b * 256) + (dir * 128) + c) * SEQ_L;

    float hv[PER_LANE], gv[PER_LANE];
    load8(hrow, grow, p, dir, hv, gv);
    const float chunk_state = st[gchunk];   // scalar broadcast

    float pp[PER_LANE], ov0[PER_LANE];
    float ca = 1.0f, cb = 0.0f;
#pragma unroll
    for (int j = 0; j < PER_LANE; ++j) {
        float a, bb; coeffs(gv[j], hv[j], a, bb);
        cb = a * cb + bb;
        ca = a * ca;
        ov0[j] = cb;
        pp[j]  = ca;
    }

    // inclusive wave scan of (a,b) composition
    float pa = ca, pb = cb;
#pragma unroll
    for (int d = 1; d < 64; d <<= 1) {
        const float oa = __shfl_up(pa, d);
        const float ob = __shfl_up(pb, d);
        if (lane >= d) {
            pb = pa * ob + pb;   // pre-update pa
            pa = pa * oa;
        }
    }
    // exclusive prefix -> state entering this lane
    float ea = __shfl_up(pa, 1);
    float eb = __shfl_up(pb, 1);
    if (lane == 0) { ea = 1.0f; eb = 0.0f; }
    const float stl = ea * chunk_state + eb;

    float ov[PER_LANE];
#pragma unroll
    for (int j = 0; j < PER_LANE; ++j) ov[j] = ov0[j] + stl * pp[j];

    // store in physical order
    if (dir == 0) {
        *(float4*)(orow + p)     = make_float4(ov[0], ov[1], ov[2], ov[3]);
        *(float4*)(orow + p + 4) = make_float4(ov[4], ov[5], ov[6], ov[7]);
    } else {
        *(float4*)(orow + p)     = make_float4(ov[7], ov[6], ov[5], ov[4]);
        *(float4*)(orow + p + 4) = make_float4(ov[3], ov[2], ov[1], ov[0]);
    }
}

extern "C" void kernel_launch(void* const* d_in, const int* in_sizes, int n_in,
                              void* d_out, int out_size, void* d_ws, size_t ws_size,
                              hipStream_t stream) {
    const float* x = (const float*)d_in[0];
    float* out = (float*)d_out;
    float2* agg = (float2*)d_ws;                                    // 32768 float2 = 256 KiB
    float* st   = (float*)((char*)d_ws + NCHUNK_TOTAL * sizeof(float2)); // 128 KiB

    k_agg   <<<NCHUNK_TOTAL / 4, 256, 0, stream>>>(x, agg);
    k_states<<<NSEQ / 256,       256, 0, stream>>>(agg, st);
    k_apply <<<NCHUNK_TOTAL / 4, 256, 0, stream>>>(x, st, out);
}

// Round 6
// 222.523 us; speedup vs baseline: 1.0241x; 1.0241x over previous
//
#include <hip/hip_runtime.h>
#include <math.h>

// minGRU bidirectional scan — single pass, R2 structure, lean VALU.
// x: [8, 512, 8192] fp32. out: [8, 256, 8192] fp32.
//   e = exp(g); a = 1/(1+e) = sigmoid(-g); z = e*a = sigmoid(g)
//   b = z * g(h), g(h) = h>=0 ? h+1 : exp(h);  H_t = a*H_{t-1} + b
// dir is a template parameter: backward reversal is static register renaming.

#define SEQ_L 8192
#define NTHREADS 256
#define PER_THREAD 8
#define TILE (NTHREADS * PER_THREAD)   // 2048
#define NTILES (SEQ_L / TILE)          // 4

typedef float vf4 __attribute__((ext_vector_type(4)));   // native vector for nontemporal store

template<int DIR>
__device__ __forceinline__ void run_seq(const float* __restrict__ hrow,
                                        const float* __restrict__ grow,
                                        float* __restrict__ orow,
                                        const int tid, const int lane, const int wave,
                                        float (&sA)[2][4], float (&sB)[2][4]) {
    float carry = 0.0f;

    // prefetch tile 0
    const int b0 = tid * PER_THREAD;
    const int i0 = DIR ? (SEQ_L - b0 - PER_THREAD) : b0;
    float4 nh0 = *(const float4*)(hrow + i0);
    float4 nh1 = *(const float4*)(hrow + i0 + 4);
    float4 ng0 = *(const float4*)(grow + i0);
    float4 ng1 = *(const float4*)(grow + i0 + 4);

#pragma unroll
    for (int t = 0; t < NTILES; ++t) {
        const float4 h0 = nh0, h1 = nh1, g0 = ng0, g1 = ng1;

        // issue next tile's loads before any compute
        if (t + 1 < NTILES) {
            const int nb = (t + 1) * TILE + tid * PER_THREAD;
            const int ni = DIR ? (SEQ_L - nb - PER_THREAD) : nb;
            nh0 = *(const float4*)(hrow + ni);
            nh1 = *(const float4*)(hrow + ni + 4);
            ng0 = *(const float4*)(grow + ni);
            ng1 = *(const float4*)(grow + ni + 4);
        }

        // static unpack into scan order (free register renaming)
        float hv[PER_THREAD], gv[PER_THREAD];
        if (DIR == 0) {
            hv[0]=h0.x; hv[1]=h0.y; hv[2]=h0.z; hv[3]=h0.w;
            hv[4]=h1.x; hv[5]=h1.y; hv[6]=h1.z; hv[7]=h1.w;
            gv[0]=g0.x; gv[1]=g0.y; gv[2]=g0.z; gv[3]=g0.w;
            gv[4]=g1.x; gv[5]=g1.y; gv[6]=g1.z; gv[7]=g1.w;
        } else {
            hv[0]=h1.w; hv[1]=h1.z; hv[2]=h1.y; hv[3]=h1.x;
            hv[4]=h0.w; hv[5]=h0.z; hv[6]=h0.y; hv[7]=h0.x;
            gv[0]=g1.w; gv[1]=g1.z; gv[2]=g1.y; gv[3]=g1.x;
            gv[4]=g0.w; gv[5]=g0.z; gv[6]=g0.y; gv[7]=g0.x;
        }

        // coefficients + local scan from zero; keep (ov0, pp)
        float pp[PER_THREAD], ov0[PER_THREAD];
        float ca = 1.0f, cb = 0.0f;
#pragma unroll
        for (int j = 0; j < PER_THREAD; ++j) {
            const float e  = __expf(gv[j]);                    // exp(g); |g|<~6, no overflow
            const float a  = __builtin_amdgcn_rcpf(1.0f + e);  // sigmoid(-g), raw v_rcp
            const float z  = e * a;                            // sigmoid(g)
            const float hh = hv[j];
            const float eh = __expf(hh);
            const float gf = (hh >= 0.0f) ? (hh + 1.0f) : eh;
            const float bb = z * gf;
            cb = fmaf(a, cb, bb);
            ca *= a;
            ov0[j] = cb;
            pp[j]  = ca;
        }

        // inclusive wave scan of (a,b) pair composition
        float pa = ca, pb = cb;
#pragma unroll
        for (int d = 1; d < 64; d <<= 1) {
            const float oa = __shfl_up(pa, d);
            const float ob = __shfl_up(pb, d);
            if (lane >= d) {
                pb = fmaf(pa, ob, pb);   // pre-update pa
                pa *= oa;
            }
        }

        const int buf = t & 1;
        if (lane == 63) { sA[buf][wave] = pa; sB[buf][wave] = pb; }
        __syncthreads();   // single barrier per tile (double-buffered sA/sB)

        // state entering this thread
        float st = carry;
        for (int w = 0; w < wave; ++w) st = fmaf(sA[buf][w], st, sB[buf][w]);
        float ea = __shfl_up(pa, 1);
        float eb = __shfl_up(pb, 1);
        if (lane == 0) { ea = 1.0f; eb = 0.0f; }
        st = fmaf(ea, st, eb);

        // outputs via correction; nontemporal stores (output never re-read)
        const int base = t * TILE + tid * PER_THREAD;
        if (DIR == 0) {
            vf4 o0 = { fmaf(st, pp[0], ov0[0]), fmaf(st, pp[1], ov0[1]),
                       fmaf(st, pp[2], ov0[2]), fmaf(st, pp[3], ov0[3]) };
            vf4 o1 = { fmaf(st, pp[4], ov0[4]), fmaf(st, pp[5], ov0[5]),
                       fmaf(st, pp[6], ov0[6]), fmaf(st, pp[7], ov0[7]) };
            __builtin_nontemporal_store(o0, (vf4*)(orow + base));
            __builtin_nontemporal_store(o1, (vf4*)(orow + base + 4));
        } else {
            const int p = SEQ_L - base - PER_THREAD;
            vf4 o0 = { fmaf(st, pp[7], ov0[7]), fmaf(st, pp[6], ov0[6]),
                       fmaf(st, pp[5], ov0[5]), fmaf(st, pp[4], ov0[4]) };
            vf4 o1 = { fmaf(st, pp[3], ov0[3]), fmaf(st, pp[2], ov0[2]),
                       fmaf(st, pp[1], ov0[1]), fmaf(st, pp[0], ov0[0]) };
            __builtin_nontemporal_store(o0, (vf4*)(orow + p));
            __builtin_nontemporal_store(o1, (vf4*)(orow + p + 4));
        }

        // fold wave aggregates into carry for next tile
        float nc = carry;
#pragma unroll
        for (int w = 0; w < 4; ++w) nc = fmaf(sA[buf][w], nc, sB[buf][w]);
        carry = nc;
        // no trailing barrier: double-buffered sA/sB
    }
}

__global__ __launch_bounds__(NTHREADS, 8) void mingru_scan_kernel(
    const float* __restrict__ x, float* __restrict__ out) {
    const int blk = blockIdx.x;          // 0..2047
    const int dir = blk >> 10;           // 0 fwd, 1 bwd
    const int s   = blk & 1023;
    const int b   = s >> 7;              // batch
    const int c   = s & 127;             // channel

    const int tid  = threadIdx.x;
    const int lane = tid & 63;
    const int wave = tid >> 6;

    const float* hrow = x + (size_t)((b * 512) + (dir * 256) + c) * SEQ_L;
    const float* grow = hrow + (size_t)128 * SEQ_L;
    float* orow = out + (size_t)((b * 256) + (dir * 128) + c) * SEQ_L;

    __shared__ float sA[2][4];
    __shared__ float sB[2][4];

    if (dir == 0) run_seq<0>(hrow, grow, orow, tid, lane, wave, sA, sB);
    else          run_seq<1>(hrow, grow, orow, tid, lane, wave, sA, sB);
}

extern "C" void kernel_launch(void* const* d_in, const int* in_sizes, int n_in,
                              void* d_out, int out_size, void* d_ws, size_t ws_size,
                              hipStream_t stream) {
    const float* x = (const float*)d_in[0];
    float* out = (float*)d_out;
    mingru_scan_kernel<<<2048, NTHREADS, 0, stream>>>(x, out);
}